// Round 16
// baseline (1223.741 us; speedup 1.0000x reference)
//
#include <hip/hip_runtime.h>

typedef __bf16 bf16x8 __attribute__((ext_vector_type(8)));
typedef __bf16 bf16x4 __attribute__((ext_vector_type(4)));
typedef float  f32x4  __attribute__((ext_vector_type(4)));

#define N_NODES  50000
#define N_EDGES  500000
#define EB       128         // edges per k_msg block
#define EP       500096      // padded edge count (multiple of EB)
#define NCH      12          // 16B chunks per edge row (96 bf16)
#define N_GRAPHS 1024
#define NF       128
#define IN_DIM   92
#define N_LAYERS 5
#define SPANMAX  256

__device__ __forceinline__ float sigmoidf_(float x) { return 1.0f / (1.0f + __expf(-x)); }
__device__ __forceinline__ float softplusf_(float x) {
    return fmaxf(x, 0.0f) + __logf(1.0f + __expf(-fabsf(x)));
}
__device__ __forceinline__ float siluf_(float x) { return x * sigmoidf_(x); }

// ---------------------------------------------------------------------------
// Fold the edge-MLP second stage into layer weights (parallel, R15).
// ---------------------------------------------------------------------------
__global__ void __launch_bounds__(256) k_fold(const float* __restrict__ Wg,
    const float* __restrict__ Wc, const float* __restrict__ rbW2,
    const float* __restrict__ rbB2, const float* __restrict__ shW2,
    const float* __restrict__ shB2, const float* __restrict__ bg,
    const float* __restrict__ bc, float* __restrict__ Wfold,
    float* __restrict__ bF) {
    int lg = blockIdx.x / 48, chunk = blockIdx.x % 48;
    int l = lg >> 1, g = lg & 1;
    const float* W = (g ? Wc : Wg) + (size_t)l * 384 * 128;
    int idx = chunk * 256 + threadIdx.x;
    int r = idx >> 7, n = idx & 127;
    float s = 0.f;
    if (r < 64) {
        for (int o = 0; o < 64; ++o) s += rbW2[r * 64 + o] * W[(256 + o) * 128 + n];
    } else {
        int j = r - 64;
        for (int o = 0; o < 64; ++o) s += shW2[j * 64 + o] * W[(320 + o) * 128 + n];
    }
    Wfold[(size_t)lg * 12288 + idx] = s;
    if (chunk == 0 && threadIdx.x < 128) {
        const float* bsrc = (g ? bc : bg) + l * 128;
        float b = bsrc[threadIdx.x];
        for (int o = 0; o < 64; ++o) b += rbB2[o] * W[(256 + o) * 128 + threadIdx.x];
        for (int o = 0; o < 64; ++o) b += shB2[o] * W[(320 + o) * 128 + threadIdx.x];
        bF[lg * 128 + threadIdx.x] = b;
    }
}

// ---------------------------------------------------------------------------
// Weight prep: WeT = A-frags of Wfold^T; WnT = A-frags of node weights.
// ---------------------------------------------------------------------------
__global__ void __launch_bounds__(256) k_prep_w(const float* __restrict__ Wg,
                                                const float* __restrict__ Wc,
                                                const float* __restrict__ Wfold,
                                                __bf16* __restrict__ WeT,
                                                __bf16* __restrict__ WnT) {
    int t = blockIdx.x * 256 + threadIdx.x;
    if (t >= (240 + 640) * 64) return;
    int frag = t >> 6, lane = t & 63;
    int sub = lane >> 4, mm = lane & 15;
    bf16x8 v;
    if (frag < 240) {
        int lg = frag / 24; int r = frag % 24;
        int m = r / 3; int ks = r % 3;
        #pragma unroll
        for (int j = 0; j < 8; ++j) {
            int k = ks * 32 + sub * 8 + j;
            v[j] = (__bf16)Wfold[(size_t)lg * 12288 + (size_t)k * 128 + m * 16 + mm];
        }
        *(bf16x8*)(WeT + (size_t)frag * 512 + lane * 8) = v;
    } else {
        int f2 = frag - 240;
        int l = f2 / 128; int r = f2 % 128;
        int m = r >> 2; int ks = r & 3;
        int F = m * 16 + mm;
        #pragma unroll
        for (int j = 0; j < 8; ++j) {
            int k = ks * 32 + sub * 8 + j;
            float val;
            if      (F < 128) val = Wg[(size_t)l*384*128 + (size_t)k*128 + F];
            else if (F < 256) val = Wc[(size_t)l*384*128 + (size_t)k*128 + (F-128)];
            else if (F < 384) val = Wg[(size_t)l*384*128 + (size_t)(128+k)*128 + (F-256)];
            else              val = Wc[(size_t)l*384*128 + (size_t)(128+k)*128 + (F-384)];
            v[j] = (__bf16)val;
        }
        *(bf16x8*)(WnT + (size_t)f2 * 512 + lane * 8) = v;
    }
}

// ---------------------------------------------------------------------------
// CSR build
// ---------------------------------------------------------------------------
__global__ void __launch_bounds__(256) k_deg(const int* __restrict__ dstI,
                                             int* __restrict__ deg) {
    int e = blockIdx.x * 256 + threadIdx.x;
    if (e < N_EDGES) atomicAdd(&deg[dstI[e]], 1);
}

__global__ void __launch_bounds__(1024) k_scan(const int* __restrict__ deg,
                                               int* __restrict__ cursor) {
    __shared__ int ps[1024];
    int t = threadIdx.x;
    const int C = (N_NODES + 1023) / 1024;
    int base = t * C;
    int s = 0;
    for (int i = 0; i < C; ++i) { int idx = base + i; if (idx < N_NODES) s += deg[idx]; }
    ps[t] = s;
    __syncthreads();
    for (int off = 1; off < 1024; off <<= 1) {
        int v = 0;
        if (t >= off) v = ps[t - off];
        __syncthreads();
        if (t >= off) ps[t] += v;
        __syncthreads();
    }
    int run = (t > 0) ? ps[t - 1] : 0;
    for (int i = 0; i < C; ++i) {
        int idx = base + i;
        if (idx < N_NODES) { cursor[idx] = run; run += deg[idx]; }
    }
}

// ---------------------------------------------------------------------------
// Scatter: sorted dst, pre-scaled (dst,src) row offsets (256 elems/node),
// and gathered per-edge raw features in sorted order.
// ---------------------------------------------------------------------------
__global__ void __launch_bounds__(256) k_scatter(const int* __restrict__ srcI,
                                                 const int* __restrict__ dstI,
                                                 const float* __restrict__ edist,
                                                 const float* __restrict__ sh,
                                                 int* __restrict__ cursor,
                                                 int* __restrict__ dstS,
                                                 int2* __restrict__ sdS,
                                                 float* __restrict__ distS,
                                                 float* __restrict__ shS) {
    int e = blockIdx.x * 256 + threadIdx.x;
    if (e >= N_EDGES) return;
    int d = dstI[e];
    int p = atomicAdd(&cursor[d], 1);
    dstS[p] = d;
    sdS[p] = make_int2(d * 256, srcI[e] * 256);
    distS[p] = edist[e];
    #pragma unroll
    for (int i = 0; i < 9; ++i) shS[(size_t)p * 9 + i] = sh[(size_t)e * 9 + i];
}

// ---------------------------------------------------------------------------
// Pad entries [N_EDGES, EP).
// ---------------------------------------------------------------------------
__global__ void __launch_bounds__(128) k_pad(int* __restrict__ dstS,
                                             int2* __restrict__ sdS,
                                             char* __restrict__ ea2) {
    int i = threadIdx.x;
    if (i < EP - N_EDGES) {
        dstS[N_EDGES + i] = N_NODES;
        sdS[N_EDGES + i] = make_int2((N_NODES - 1) * 256, 0);
        uint4 z = {0, 0, 0, 0};
        for (int p = 0; p < NCH; ++p)
            *(uint4*)(ea2 + ((size_t)p * EP + N_EDGES + i) * 16) = z;
    }
}

// ---------------------------------------------------------------------------
// Atom embedding: h = x @ W_emb + b_emb (f32)
// ---------------------------------------------------------------------------
__global__ void __launch_bounds__(256) k_embed(const float* __restrict__ x,
                                               const float* __restrict__ W,
                                               const float* __restrict__ b,
                                               float* __restrict__ h) {
    int tid = threadIdx.x;
    int f = tid & 127;
    int nb = blockIdx.x * 8 + (tid >> 7) * 4;
    const float* x0 = x + (size_t)nb * IN_DIM;
    float a0 = b[f], a1 = a0, a2 = a0, a3 = a0;
    #pragma unroll 4
    for (int k = 0; k < IN_DIM; ++k) {
        float wv = W[k * NF + f];
        a0 = fmaf(x0[k], wv, a0);
        a1 = fmaf(x0[IN_DIM + k], wv, a1);
        a2 = fmaf(x0[2 * IN_DIM + k], wv, a2);
        a3 = fmaf(x0[3 * IN_DIM + k], wv, a3);
    }
    float accs[4] = {a0, a1, a2, a3};
    #pragma unroll
    for (int r = 0; r < 4; ++r)
        h[(size_t)(nb + r) * NF + f] = accs[r];
}

// ---------------------------------------------------------------------------
// Edge hidden features eh[e][96] — streaming, chunk-plane output.
// ---------------------------------------------------------------------------
__global__ void __launch_bounds__(256) k_edge(const float* __restrict__ distS,
    const float* __restrict__ shS,
    const float* __restrict__ shW1, const float* __restrict__ shB1,
    const float* __restrict__ rbW1, const float* __restrict__ rbB1,
    char* __restrict__ ea2) {
    __shared__ float wf[4480];
    int tid = threadIdx.x;
    int p = blockIdx.x * 256 + tid;
    bool pv = p < N_EDGES;
    int pc = pv ? p : 0;
    float dv = distS[pc];
    float shv[9];
    #pragma unroll
    for (int i = 0; i < 9; ++i) shv[i] = shS[(size_t)pc * 9 + i];
    for (int i = tid; i < 288;  i += 256) wf[i]        = shW1[i];
    for (int i = tid; i < 32;   i += 256) wf[288 + i]  = shB1[i];
    for (int i = tid; i < 4096; i += 256) wf[320 + i]  = rbW1[i];
    for (int i = tid; i < 64;   i += 256) wf[4416 + i] = rbB1[i];
    __syncthreads();
    if (!pv) return;

    const float* W1 = wf + 320; const float* B1 = wf + 4416;
    float invd = 1.0f / dv;
    const float step = (1.4f - 0.125f) / 63.0f;
    const float gam = 1.0f / (step * step);
    float hid[64];
    #pragma unroll
    for (int j = 0; j < 64; ++j) hid[j] = B1[j];
    for (int i = 0; i < 64; ++i) {
        float c = 0.125f + i * step;
        float d = invd - c;
        float r = __expf(-gam * d * d);
        #pragma unroll
        for (int j = 0; j < 64; ++j) hid[j] += r * W1[i * 64 + j];
    }
    #pragma unroll
    for (int o8 = 0; o8 < 8; ++o8) {
        bf16x8 v;
        #pragma unroll
        for (int j = 0; j < 8; ++j) v[j] = (__bf16)siluf_(hid[o8 * 8 + j]);
        *(bf16x8*)(ea2 + ((size_t)o8 * EP + p) * 16) = v;
    }
    const float* sW1 = wf; const float* sB1 = wf + 288;
    float h2[32];
    #pragma unroll
    for (int j = 0; j < 32; ++j) h2[j] = sB1[j];
    #pragma unroll
    for (int i = 0; i < 9; ++i) {
        float si = shv[i];
        #pragma unroll
        for (int j = 0; j < 32; ++j) h2[j] += si * sW1[i * 32 + j];
    }
    #pragma unroll
    for (int o8 = 0; o8 < 4; ++o8) {
        bf16x8 v;
        #pragma unroll
        for (int j = 0; j < 8; ++j) v[j] = (__bf16)siluf_(h2[o8 * 8 + j]);
        *(bf16x8*)(ea2 + ((size_t)(8 + o8) * EP + p) * 16) = v;
    }
}

// ---------------------------------------------------------------------------
// Per-node GEMM -> f32 buffers (k_msg consumes without conversion):
// NBdF[node][g(2)][F(128)] f32 : g=0 -> h@Wg_d + bFg, g=1 -> h@Wc_d + bFc
// NBsF[node][g(2)][F(128)] f32 : g=0 -> h@Wg_s,       g=1 -> h@Wc_s
// ---------------------------------------------------------------------------
__global__ void __launch_bounds__(256) k_node(const float* __restrict__ h,
                                              const __bf16* __restrict__ WnT,
                                              const float* __restrict__ bgl,
                                              const float* __restrict__ bcl,
                                              float* __restrict__ NBdF,
                                              float* __restrict__ NBsF, int layer) {
    int tid = threadIdx.x, lane = tid & 63, w = tid >> 6;
    int sub = lane >> 4, rA = lane & 15;
    int node0 = blockIdx.x * 32;
    bf16x8 Bf[2][4];
    #pragma unroll
    for (int nt = 0; nt < 2; ++nt)
        #pragma unroll
        for (int ks = 0; ks < 4; ++ks) {
            int node = min(node0 + nt * 16 + rA, N_NODES - 1);
            const float* hr = h + (size_t)node * 128 + ks * 32 + sub * 8;
            f32x4 u0 = *(const f32x4*)hr;
            f32x4 u1 = *(const f32x4*)(hr + 4);
            bf16x8 bv;
            bv[0] = (__bf16)u0[0]; bv[1] = (__bf16)u0[1];
            bv[2] = (__bf16)u0[2]; bv[3] = (__bf16)u0[3];
            bv[4] = (__bf16)u1[0]; bv[5] = (__bf16)u1[1];
            bv[6] = (__bf16)u1[2]; bv[7] = (__bf16)u1[3];
            Bf[nt][ks] = bv;
        }
    const __bf16* Wbase = WnT + (size_t)layer * 128 * 512;
    f32x4 acc[8][2];
    f32x4 zz = {0.f, 0.f, 0.f, 0.f};
    #pragma unroll
    for (int mt = 0; mt < 8; ++mt) { acc[mt][0] = zz; acc[mt][1] = zz; }
    for (int mt = 0; mt < 8; ++mt) {
        int gm = w * 8 + mt;
        bf16x8 Af[4];
        #pragma unroll
        for (int ks = 0; ks < 4; ++ks)
            Af[ks] = *(const bf16x8*)(Wbase + (size_t)(gm * 4 + ks) * 512 + lane * 8);
        #pragma unroll
        for (int nt = 0; nt < 2; ++nt) {
            f32x4 a = acc[mt][nt];
            #pragma unroll
            for (int ks = 0; ks < 4; ++ks)
                a = __builtin_amdgcn_mfma_f32_16x16x32_bf16(Af[ks], Bf[nt][ks], a, 0, 0, 0);
            acc[mt][nt] = a;
        }
    }
    #pragma unroll
    for (int mt = 0; mt < 8; ++mt) {
        int F = (w * 8 + mt) * 16 + sub * 4;     // global feature 0..511
        int part = F >> 7;                       // 0=gd 1=cd 2=gs 3=cs
        f32x4 bias = zz;
        if (part == 0)      bias = *(const f32x4*)(bgl + (F & 127));
        else if (part == 1) bias = *(const f32x4*)(bcl + (F & 127));
        float* buf = (part < 2) ? NBdF : NBsF;
        int off = (part & 1) * 128 + (F & 127);
        #pragma unroll
        for (int nt = 0; nt < 2; ++nt) {
            int node = node0 + nt * 16 + rA;
            if (node >= N_NODES) continue;
            f32x4 vv = acc[mt][nt];
            vv[0] += bias[0]; vv[1] += bias[1]; vv[2] += bias[2]; vv[3] += bias[3];
            *(f32x4*)(buf + (size_t)node * 256 + off) = vv;
        }
    }
}

// ---------------------------------------------------------------------------
// Message layer, dst-sorted, all blocks full. f32 NB: dst-side term enters
// via the MFMA C-operand (zero VALU); epilogue = 8 adds + gate math.
// ---------------------------------------------------------------------------
__global__ void __launch_bounds__(512) k_msg(
    const char* __restrict__ ea2, const int* __restrict__ dstS,
    const int2* __restrict__ sdS, const __bf16* __restrict__ WeT,
    const float* __restrict__ NBdF, const float* __restrict__ NBsF,
    float* __restrict__ h, int layer)
{
    __shared__ __align__(16) float mF[EB * 128];   // 64 KB messages (XOR-swizzled)
    __shared__ int rs[SPANMAX], re[SPANMAX];
    int tid = threadIdx.x, lane = tid & 63, w = tid >> 6;
    int sub = lane >> 4, rA = lane & 15;
    int e0 = blockIdx.x * EB;
    int Fb = w * 16 + sub * 4;                     // wave-local feature base
    int n0 = dstS[e0];

    // run-boundary tables (gap-fill by run-starter; no init barrier needed)
    if (tid < EB) {
        int d = dstS[e0 + tid];
        int di = min(d - n0, SPANMAX - 1);
        if (tid == 0 || dstS[e0 + tid - 1] != d) {
            rs[di] = tid;
            if (tid > 0) {
                int dp = dstS[e0 + tid - 1];
                for (int g = dp + 1; g < d && (g - n0) < SPANMAX; ++g) {
                    rs[g - n0] = 0; re[g - n0] = 0;
                }
            }
        }
        if (tid == EB - 1 || dstS[e0 + tid + 1] != d) re[di] = tid + 1;
    }

    // folded edge-weight A-frags (registers, L2-resident)
    bf16x8 Ag[3], Ac[3];
    {
        const __bf16* bg_ = WeT + (size_t)(((layer * 2 + 0) * 8 + w) * 3) * 512;
        const __bf16* bc_ = WeT + (size_t)(((layer * 2 + 1) * 8 + w) * 3) * 512;
        #pragma unroll
        for (int ks = 0; ks < 3; ++ks) {
            Ag[ks] = *(const bf16x8*)(bg_ + ks * 512 + lane * 8);
            Ac[ks] = *(const bf16x8*)(bc_ + ks * 512 + lane * 8);
        }
    }

    // hoisted loop-invariant bases
    const char* eb0 = ea2 + ((size_t)(0 + sub) * EP + e0 + rA) * 16;
    const char* eb1 = ea2 + ((size_t)(4 + sub) * EP + e0 + rA) * 16;
    const char* eb2 = ea2 + ((size_t)(8 + sub) * EP + e0 + rA) * 16;
    const int2* sdp = sdS + e0 + rA;
    const float* nbd = NBdF + Fb;
    const float* nbs = NBsF + Fb;
    char* mfp = (char*)mF + rA * 512 + ((w * 64 + sub * 16) ^ ((rA & 7) << 4));

    f32x4 zz = {0.f, 0.f, 0.f, 0.f};
    // depth-2 pipelined register sets (indices fold to constants under unroll)
    bf16x8 bfr[2][3];
    f32x4 dvG[2], dvC[2], svG[2], svC[2];

    // prologue: load nt=0
    {
        int2 sd = sdp[0];
        bfr[0][0] = *(const bf16x8*)(eb0);
        bfr[0][1] = *(const bf16x8*)(eb1);
        bfr[0][2] = *(const bf16x8*)(eb2);
        dvG[0] = *(const f32x4*)(nbd + sd.x);
        dvC[0] = *(const f32x4*)(nbd + sd.x + 128);
        svG[0] = *(const f32x4*)(nbs + sd.y);
        svC[0] = *(const f32x4*)(nbs + sd.y + 128);
    }
    #pragma unroll
    for (int nt = 0; nt < EB / 16; ++nt) {
        int cur = nt & 1, nxt = cur ^ 1;
        if (nt + 1 < EB / 16) {   // prefetch next sub-tile
            int2 sd = sdp[(nt + 1) * 16];
            bfr[nxt][0] = *(const bf16x8*)(eb0 + (nt + 1) * 256);
            bfr[nxt][1] = *(const bf16x8*)(eb1 + (nt + 1) * 256);
            bfr[nxt][2] = *(const bf16x8*)(eb2 + (nt + 1) * 256);
            dvG[nxt] = *(const f32x4*)(nbd + sd.x);
            dvC[nxt] = *(const f32x4*)(nbd + sd.x + 128);
            svG[nxt] = *(const f32x4*)(nbs + sd.y);
            svC[nxt] = *(const f32x4*)(nbs + sd.y + 128);
        }
        // dst-side node term enters as the MFMA C-init (free)
        f32x4 aG = dvG[cur], aC = dvC[cur];
        #pragma unroll
        for (int ks = 0; ks < 3; ++ks) {
            aG = __builtin_amdgcn_mfma_f32_16x16x32_bf16(Ag[ks], bfr[cur][ks], aG, 0, 0, 0);
            aC = __builtin_amdgcn_mfma_f32_16x16x32_bf16(Ac[ks], bfr[cur][ks], aC, 0, 0, 0);
        }
        f32x4 mv;
        #pragma unroll
        for (int r = 0; r < 4; ++r) {
            float gi = aG[r] + svG[cur][r];
            float ci = aC[r] + svC[cur][r];
            mv[r] = sigmoidf_(gi) * softplusf_(ci);
        }
        *(f32x4*)(mfp + nt * 8192) = mv;
    }
    __syncthreads();
    // segment-sum over runs -> h (16B feature granularity)
    int span = min(dstS[e0 + EB - 1] - n0 + 1, SPANMAX);
    int items = span * 32;
    for (int it = tid; it < items; it += 512) {
        int ln = it >> 5, fqq = it & 31;
        int rs_ = rs[ln], re_ = re[ln];
        f32x4 s = zz;
        for (int e = rs_; e < re_; ++e) {
            f32x4 v = *(const f32x4*)((char*)mF + e * 512 + ((fqq * 16) ^ ((e & 7) << 4)));
            s[0] += v[0]; s[1] += v[1]; s[2] += v[2]; s[3] += v[3];
        }
        int node = n0 + ln;
        float* dp = h + (size_t)node * 128 + fqq * 4;
        if (ln == 0 || ln == span - 1) {
            atomicAdd(dp + 0, s[0]); atomicAdd(dp + 1, s[1]);
            atomicAdd(dp + 2, s[2]); atomicAdd(dp + 3, s[3]);
        } else {
            dp[0] += s[0]; dp[1] += s[1]; dp[2] += s[2]; dp[3] += s[3];
        }
    }
}

// ---------------------------------------------------------------------------
// Readout
// ---------------------------------------------------------------------------
__global__ void __launch_bounds__(128) k_readout(const float* __restrict__ h,
    const int* __restrict__ batch, const float* __restrict__ W1,
    const float* __restrict__ b1, const float* __restrict__ W2,
    const float* __restrict__ b2, float* __restrict__ out) {
    int g = blockIdx.x, tid = threadIdx.x;
    __shared__ int se[2];
    __shared__ float pl[NF];
    __shared__ float red[2];
    if (tid < 2) {
        int target = g + tid;
        int lo = 0, hi = N_NODES;
        while (lo < hi) { int mid = (lo + hi) >> 1; if (batch[mid] < target) lo = mid + 1; else hi = mid; }
        se[tid] = lo;
    }
    __syncthreads();
    int s = se[0], e = se[1];
    float sum = 0.0f;
    for (int n = s; n < e; ++n) sum += h[(size_t)n * NF + tid];
    float cnt = (float)max(e - s, 1);
    pl[tid] = sum / cnt;
    __syncthreads();
    float acc = b1[tid];
    for (int c = 0; c < NF; ++c) acc += pl[c] * W1[c * NF + tid];
    float hid = siluf_(acc);
    float v = hid * W2[tid];
    #pragma unroll
    for (int off = 32; off > 0; off >>= 1) v += __shfl_down(v, off);
    if ((tid & 63) == 0) red[tid >> 6] = v;
    __syncthreads();
    if (tid == 0) out[g] = red[0] + red[1] + b2[0];
}

// ---------------------------------------------------------------------------
extern "C" void kernel_launch(void* const* d_in, const int* in_sizes, int n_in,
                              void* d_out, int out_size, void* d_ws, size_t ws_size,
                              hipStream_t stream) {
    const float* x     = (const float*)d_in[0];
    const int*   eidx  = (const int*)d_in[1];
    const float* sh    = (const float*)d_in[2];
    const float* edist = (const float*)d_in[3];
    const int*   batch = (const int*)d_in[4];
    const float* W_emb = (const float*)d_in[5];
    const float* b_emb = (const float*)d_in[6];
    const float* shW1  = (const float*)d_in[7];
    const float* shB1  = (const float*)d_in[8];
    const float* shW2  = (const float*)d_in[9];
    const float* shB2  = (const float*)d_in[10];
    const float* rbW1  = (const float*)d_in[11];
    const float* rbB1  = (const float*)d_in[12];
    const float* rbW2  = (const float*)d_in[13];
    const float* rbB2  = (const float*)d_in[14];
    const float* Wg    = (const float*)d_in[15];
    const float* bg    = (const float*)d_in[16];
    const float* Wc    = (const float*)d_in[17];
    const float* bc    = (const float*)d_in[18];
    const float* fcW1  = (const float*)d_in[19];
    const float* fcb1  = (const float*)d_in[20];
    const float* fcW2  = (const float*)d_in[21];
    const float* fcb2  = (const float*)d_in[22];
    const int* srcI = eidx;
    const int* dstI = eidx + N_EDGES;

    char* ws = (char*)d_ws;
    // Total footprint 231.8 MB (ws_size proven >= 250.6 MB).
    float*  h     = (float*)(ws + 0);              // 25,600,512 (50001 rows; last = dummy)
    char*   ea2   = (char*)(ws + 25600512);        // 96,018,432 (12 planes x EP x 16B)
    int*    dstS  = (int*)(ws + 121618944);        //  2,000,384
    int2*   sdS   = (int2*)(ws + 123619328);       //  4,000,768 (row offsets x256)
    int*    deg   = (int*)(ws + 127620096);        //    200,000
    int*    curs  = (int*)(ws + 127820096);        //    200,000
    __bf16* WeT   = (__bf16*)(ws + 128020096);     //    245,760
    __bf16* WnT   = (__bf16*)(ws + 128265856);     //    655,360
    float*  Wfold = (float*)(ws + 128921216);      //    491,520
    float*  bF    = (float*)(ws + 129412736);      //      5,120
    float*  NBdF  = (float*)(ws + 129417856);      // 51,200,000
    float*  NBsF  = (float*)(ws + 180617856);      // 51,200,000 -> ends 231,817,856
    // distS/shS alias the NBdF region (used only BEFORE the layer loop):
    float*  distS = (float*)(ws + 129417856);      //  2,000,384
    float*  shS   = (float*)(ws + 131418240);      // 18,003,456 (ends 149.4M < NBsF)

    hipMemsetAsync(deg, 0, (size_t)N_NODES * sizeof(int), stream);
    k_fold<<<480, 256, 0, stream>>>(Wg, Wc, rbW2, rbB2, shW2, shB2, bg, bc, Wfold, bF);
    k_prep_w<<<220, 256, 0, stream>>>(Wg, Wc, Wfold, WeT, WnT);
    k_embed<<<N_NODES / 8, 256, 0, stream>>>(x, W_emb, b_emb, h);
    k_deg<<<(N_EDGES + 255) / 256, 256, 0, stream>>>(dstI, deg);
    k_scan<<<1, 1024, 0, stream>>>(deg, curs);
    k_scatter<<<(N_EDGES + 255) / 256, 256, 0, stream>>>(srcI, dstI, edist, sh, curs,
                                                         dstS, sdS, distS, shS);
    k_edge<<<(N_EDGES + 255) / 256, 256, 0, stream>>>(distS, shS, shW1, shB1,
                                                      rbW1, rbB1, ea2);
    k_pad<<<1, 128, 0, stream>>>(dstS, sdS, ea2);
    for (int l = 0; l < N_LAYERS; ++l) {
        const float* bgF = bF + (l * 2 + 0) * 128;
        const float* bcF = bF + (l * 2 + 1) * 128;
        k_node<<<(N_NODES + 31) / 32, 256, 0, stream>>>(h, WnT, bgF, bcF, NBdF, NBsF, l);
        k_msg<<<EP / EB, 512, 0, stream>>>(ea2, dstS, sdS, WeT, NBdF, NBsF, h, l);
    }
    k_readout<<<N_GRAPHS, 128, 0, stream>>>(h, batch, fcW1, fcb1, fcW2, fcb2, (float*)d_out);
}

// Round 17
// 1105.833 us; speedup vs baseline: 1.1066x; 1.1066x over previous
//
#include <hip/hip_runtime.h>

typedef __bf16 bf16x8 __attribute__((ext_vector_type(8)));
typedef __bf16 bf16x4 __attribute__((ext_vector_type(4)));
typedef float  f32x4  __attribute__((ext_vector_type(4)));

#define N_NODES  50000
#define N_EDGES  500000
#define EB       128         // edges per k_msg block
#define EP       500096      // padded edge count (multiple of EB)
#define NCH      12          // 16B chunks per edge row (96 bf16)
#define N_GRAPHS 1024
#define NF       128
#define IN_DIM   92
#define N_LAYERS 5
#define SPANMAX  256

__device__ __forceinline__ float sigmoidf_(float x) { return 1.0f / (1.0f + __expf(-x)); }
__device__ __forceinline__ float softplusf_(float x) {
    return fmaxf(x, 0.0f) + __logf(1.0f + __expf(-fabsf(x)));
}
__device__ __forceinline__ float siluf_(float x) { return x * sigmoidf_(x); }

// ---------------------------------------------------------------------------
// Fold the edge-MLP second stage into layer weights (parallel).
// ---------------------------------------------------------------------------
__global__ void __launch_bounds__(256) k_fold(const float* __restrict__ Wg,
    const float* __restrict__ Wc, const float* __restrict__ rbW2,
    const float* __restrict__ rbB2, const float* __restrict__ shW2,
    const float* __restrict__ shB2, const float* __restrict__ bg,
    const float* __restrict__ bc, float* __restrict__ Wfold,
    float* __restrict__ bF) {
    int lg = blockIdx.x / 48, chunk = blockIdx.x % 48;
    int l = lg >> 1, g = lg & 1;
    const float* W = (g ? Wc : Wg) + (size_t)l * 384 * 128;
    int idx = chunk * 256 + threadIdx.x;
    int r = idx >> 7, n = idx & 127;
    float s = 0.f;
    if (r < 64) {
        for (int o = 0; o < 64; ++o) s += rbW2[r * 64 + o] * W[(256 + o) * 128 + n];
    } else {
        int j = r - 64;
        for (int o = 0; o < 64; ++o) s += shW2[j * 64 + o] * W[(320 + o) * 128 + n];
    }
    Wfold[(size_t)lg * 12288 + idx] = s;
    if (chunk == 0 && threadIdx.x < 128) {
        const float* bsrc = (g ? bc : bg) + l * 128;
        float b = bsrc[threadIdx.x];
        for (int o = 0; o < 64; ++o) b += rbB2[o] * W[(256 + o) * 128 + threadIdx.x];
        for (int o = 0; o < 64; ++o) b += shB2[o] * W[(320 + o) * 128 + threadIdx.x];
        bF[lg * 128 + threadIdx.x] = b;
    }
}

// ---------------------------------------------------------------------------
// Weight prep: WeT = A-frags of Wfold^T; WnT = A-frags of node weights.
// ---------------------------------------------------------------------------
__global__ void __launch_bounds__(256) k_prep_w(const float* __restrict__ Wg,
                                                const float* __restrict__ Wc,
                                                const float* __restrict__ Wfold,
                                                __bf16* __restrict__ WeT,
                                                __bf16* __restrict__ WnT) {
    int t = blockIdx.x * 256 + threadIdx.x;
    if (t >= (240 + 640) * 64) return;
    int frag = t >> 6, lane = t & 63;
    int sub = lane >> 4, mm = lane & 15;
    bf16x8 v;
    if (frag < 240) {
        int lg = frag / 24; int r = frag % 24;
        int m = r / 3; int ks = r % 3;
        #pragma unroll
        for (int j = 0; j < 8; ++j) {
            int k = ks * 32 + sub * 8 + j;
            v[j] = (__bf16)Wfold[(size_t)lg * 12288 + (size_t)k * 128 + m * 16 + mm];
        }
        *(bf16x8*)(WeT + (size_t)frag * 512 + lane * 8) = v;
    } else {
        int f2 = frag - 240;
        int l = f2 / 128; int r = f2 % 128;
        int m = r >> 2; int ks = r & 3;
        int F = m * 16 + mm;
        #pragma unroll
        for (int j = 0; j < 8; ++j) {
            int k = ks * 32 + sub * 8 + j;
            float val;
            if      (F < 128) val = Wg[(size_t)l*384*128 + (size_t)k*128 + F];
            else if (F < 256) val = Wc[(size_t)l*384*128 + (size_t)k*128 + (F-128)];
            else if (F < 384) val = Wg[(size_t)l*384*128 + (size_t)(128+k)*128 + (F-256)];
            else              val = Wc[(size_t)l*384*128 + (size_t)(128+k)*128 + (F-384)];
            v[j] = (__bf16)val;
        }
        *(bf16x8*)(WnT + (size_t)f2 * 512 + lane * 8) = v;
    }
}

// ---------------------------------------------------------------------------
// CSR build
// ---------------------------------------------------------------------------
__global__ void __launch_bounds__(256) k_deg(const int* __restrict__ dstI,
                                             int* __restrict__ deg) {
    int e = blockIdx.x * 256 + threadIdx.x;
    if (e < N_EDGES) atomicAdd(&deg[dstI[e]], 1);
}

__global__ void __launch_bounds__(1024) k_scan(const int* __restrict__ deg,
                                               int* __restrict__ cursor) {
    __shared__ int ps[1024];
    int t = threadIdx.x;
    const int C = (N_NODES + 1023) / 1024;
    int base = t * C;
    int s = 0;
    for (int i = 0; i < C; ++i) { int idx = base + i; if (idx < N_NODES) s += deg[idx]; }
    ps[t] = s;
    __syncthreads();
    for (int off = 1; off < 1024; off <<= 1) {
        int v = 0;
        if (t >= off) v = ps[t - off];
        __syncthreads();
        if (t >= off) ps[t] += v;
        __syncthreads();
    }
    int run = (t > 0) ? ps[t - 1] : 0;
    for (int i = 0; i < C; ++i) {
        int idx = base + i;
        if (idx < N_NODES) { cursor[idx] = run; run += deg[idx]; }
    }
}

// ---------------------------------------------------------------------------
// Scatter: sorted dst, pre-scaled (dst,src) row offsets, and gathered raw
// per-edge features in sorted order.
// ---------------------------------------------------------------------------
__global__ void __launch_bounds__(256) k_scatter(const int* __restrict__ srcI,
                                                 const int* __restrict__ dstI,
                                                 const float* __restrict__ edist,
                                                 const float* __restrict__ sh,
                                                 int* __restrict__ cursor,
                                                 int* __restrict__ dstS,
                                                 int2* __restrict__ sdS,
                                                 float* __restrict__ distS,
                                                 float* __restrict__ shS) {
    int e = blockIdx.x * 256 + threadIdx.x;
    if (e >= N_EDGES) return;
    int d = dstI[e];
    int p = atomicAdd(&cursor[d], 1);
    dstS[p] = d;
    sdS[p] = make_int2(d * 256, srcI[e] * 256);
    distS[p] = edist[e];
    #pragma unroll
    for (int i = 0; i < 9; ++i) shS[(size_t)p * 9 + i] = sh[(size_t)e * 9 + i];
}

// ---------------------------------------------------------------------------
// Pad entries [N_EDGES, EP).
// ---------------------------------------------------------------------------
__global__ void __launch_bounds__(128) k_pad(int* __restrict__ dstS,
                                             int2* __restrict__ sdS,
                                             char* __restrict__ ea2) {
    int i = threadIdx.x;
    if (i < EP - N_EDGES) {
        dstS[N_EDGES + i] = N_NODES;
        sdS[N_EDGES + i] = make_int2((N_NODES - 1) * 256, 0);
        uint4 z = {0, 0, 0, 0};
        for (int p = 0; p < NCH; ++p)
            *(uint4*)(ea2 + ((size_t)p * EP + N_EDGES + i) * 16) = z;
    }
}

// ---------------------------------------------------------------------------
// Atom embedding: h = x @ W_emb + b_emb (f32)
// ---------------------------------------------------------------------------
__global__ void __launch_bounds__(256) k_embed(const float* __restrict__ x,
                                               const float* __restrict__ W,
                                               const float* __restrict__ b,
                                               float* __restrict__ h) {
    int tid = threadIdx.x;
    int f = tid & 127;
    int nb = blockIdx.x * 8 + (tid >> 7) * 4;
    const float* x0 = x + (size_t)nb * IN_DIM;
    float a0 = b[f], a1 = a0, a2 = a0, a3 = a0;
    #pragma unroll 4
    for (int k = 0; k < IN_DIM; ++k) {
        float wv = W[k * NF + f];
        a0 = fmaf(x0[k], wv, a0);
        a1 = fmaf(x0[IN_DIM + k], wv, a1);
        a2 = fmaf(x0[2 * IN_DIM + k], wv, a2);
        a3 = fmaf(x0[3 * IN_DIM + k], wv, a3);
    }
    float accs[4] = {a0, a1, a2, a3};
    #pragma unroll
    for (int r = 0; r < 4; ++r)
        h[(size_t)(nb + r) * NF + f] = accs[r];
}

// ---------------------------------------------------------------------------
// Edge hidden features eh[e][96] — streaming, chunk-plane output.
// ---------------------------------------------------------------------------
__global__ void __launch_bounds__(256) k_edge(const float* __restrict__ distS,
    const float* __restrict__ shS,
    const float* __restrict__ shW1, const float* __restrict__ shB1,
    const float* __restrict__ rbW1, const float* __restrict__ rbB1,
    char* __restrict__ ea2) {
    __shared__ float wf[4480];
    int tid = threadIdx.x;
    int p = blockIdx.x * 256 + tid;
    bool pv = p < N_EDGES;
    int pc = pv ? p : 0;
    float dv = distS[pc];
    float shv[9];
    #pragma unroll
    for (int i = 0; i < 9; ++i) shv[i] = shS[(size_t)pc * 9 + i];
    for (int i = tid; i < 288;  i += 256) wf[i]        = shW1[i];
    for (int i = tid; i < 32;   i += 256) wf[288 + i]  = shB1[i];
    for (int i = tid; i < 4096; i += 256) wf[320 + i]  = rbW1[i];
    for (int i = tid; i < 64;   i += 256) wf[4416 + i] = rbB1[i];
    __syncthreads();
    if (!pv) return;

    const float* W1 = wf + 320; const float* B1 = wf + 4416;
    float invd = 1.0f / dv;
    const float step = (1.4f - 0.125f) / 63.0f;
    const float gam = 1.0f / (step * step);
    float hid[64];
    #pragma unroll
    for (int j = 0; j < 64; ++j) hid[j] = B1[j];
    for (int i = 0; i < 64; ++i) {
        float c = 0.125f + i * step;
        float d = invd - c;
        float r = __expf(-gam * d * d);
        #pragma unroll
        for (int j = 0; j < 64; ++j) hid[j] += r * W1[i * 64 + j];
    }
    #pragma unroll
    for (int o8 = 0; o8 < 8; ++o8) {
        bf16x8 v;
        #pragma unroll
        for (int j = 0; j < 8; ++j) v[j] = (__bf16)siluf_(hid[o8 * 8 + j]);
        *(bf16x8*)(ea2 + ((size_t)o8 * EP + p) * 16) = v;
    }
    const float* sW1 = wf; const float* sB1 = wf + 288;
    float h2[32];
    #pragma unroll
    for (int j = 0; j < 32; ++j) h2[j] = sB1[j];
    #pragma unroll
    for (int i = 0; i < 9; ++i) {
        float si = shv[i];
        #pragma unroll
        for (int j = 0; j < 32; ++j) h2[j] += si * sW1[i * 32 + j];
    }
    #pragma unroll
    for (int o8 = 0; o8 < 4; ++o8) {
        bf16x8 v;
        #pragma unroll
        for (int j = 0; j < 8; ++j) v[j] = (__bf16)siluf_(h2[o8 * 8 + j]);
        *(bf16x8*)(ea2 + ((size_t)(8 + o8) * EP + p) * 16) = v;
    }
}

// ---------------------------------------------------------------------------
// Per-node GEMM -> hybrid buffers:
// NBdF[node][g(2)][F(128)] f32  : dst side (sorted access, MFMA C-init)
// NBs2[node][fq][8]       bf16  : src side [gs(4)|cs(4)] (random gather)
// ---------------------------------------------------------------------------
__global__ void __launch_bounds__(256) k_node(const float* __restrict__ h,
                                              const __bf16* __restrict__ WnT,
                                              const float* __restrict__ bgl,
                                              const float* __restrict__ bcl,
                                              float* __restrict__ NBdF,
                                              __bf16* __restrict__ NBs2, int layer) {
    int tid = threadIdx.x, lane = tid & 63, w = tid >> 6;
    int sub = lane >> 4, rA = lane & 15;
    int node0 = blockIdx.x * 32;
    bf16x8 Bf[2][4];
    #pragma unroll
    for (int nt = 0; nt < 2; ++nt)
        #pragma unroll
        for (int ks = 0; ks < 4; ++ks) {
            int node = min(node0 + nt * 16 + rA, N_NODES - 1);
            const float* hr = h + (size_t)node * 128 + ks * 32 + sub * 8;
            f32x4 u0 = *(const f32x4*)hr;
            f32x4 u1 = *(const f32x4*)(hr + 4);
            bf16x8 bv;
            bv[0] = (__bf16)u0[0]; bv[1] = (__bf16)u0[1];
            bv[2] = (__bf16)u0[2]; bv[3] = (__bf16)u0[3];
            bv[4] = (__bf16)u1[0]; bv[5] = (__bf16)u1[1];
            bv[6] = (__bf16)u1[2]; bv[7] = (__bf16)u1[3];
            Bf[nt][ks] = bv;
        }
    const __bf16* Wbase = WnT + (size_t)layer * 128 * 512;
    f32x4 acc[8][2];
    f32x4 zz = {0.f, 0.f, 0.f, 0.f};
    #pragma unroll
    for (int mt = 0; mt < 8; ++mt) { acc[mt][0] = zz; acc[mt][1] = zz; }
    for (int mt = 0; mt < 8; ++mt) {
        int gm = w * 8 + mt;
        bf16x8 Af[4];
        #pragma unroll
        for (int ks = 0; ks < 4; ++ks)
            Af[ks] = *(const bf16x8*)(Wbase + (size_t)(gm * 4 + ks) * 512 + lane * 8);
        #pragma unroll
        for (int nt = 0; nt < 2; ++nt) {
            f32x4 a = acc[mt][nt];
            #pragma unroll
            for (int ks = 0; ks < 4; ++ks)
                a = __builtin_amdgcn_mfma_f32_16x16x32_bf16(Af[ks], Bf[nt][ks], a, 0, 0, 0);
            acc[mt][nt] = a;
        }
    }
    #pragma unroll
    for (int mt = 0; mt < 8; ++mt) {
        int F = (w * 8 + mt) * 16 + sub * 4;     // global feature 0..511
        int part = F >> 7;                       // 0=gd 1=cd 2=gs 3=cs
        f32x4 bias = zz;
        if (part == 0)      bias = *(const f32x4*)(bgl + (F & 127));
        else if (part == 1) bias = *(const f32x4*)(bcl + (F & 127));
        #pragma unroll
        for (int nt = 0; nt < 2; ++nt) {
            int node = node0 + nt * 16 + rA;
            if (node >= N_NODES) continue;
            f32x4 vv = acc[mt][nt];
            vv[0] += bias[0]; vv[1] += bias[1]; vv[2] += bias[2]; vv[3] += bias[3];
            if (part < 2) {
                *(f32x4*)(NBdF + (size_t)node * 256 + (part & 1) * 128 + (F & 127)) = vv;
            } else {
                int fq = (F & 127) >> 2;
                bf16x4 bv;
                bv[0] = (__bf16)vv[0]; bv[1] = (__bf16)vv[1];
                bv[2] = (__bf16)vv[2]; bv[3] = (__bf16)vv[3];
                *(bf16x4*)(NBs2 + (size_t)node * 256 + fq * 8 + (part & 1) * 4) = bv;
            }
        }
    }
}

// ---------------------------------------------------------------------------
// Message layer, dst-sorted, all blocks full. Hybrid NB: f32 dst-side term
// enters via the MFMA C-operand (zero VALU); bf16 src-side keeps gather
// traffic small. Epilogue = 8 cvt+adds + gate math.
// ---------------------------------------------------------------------------
__global__ void __launch_bounds__(512) k_msg(
    const char* __restrict__ ea2, const int* __restrict__ dstS,
    const int2* __restrict__ sdS, const __bf16* __restrict__ WeT,
    const float* __restrict__ NBdF, const __bf16* __restrict__ NBs2,
    float* __restrict__ h, int layer)
{
    __shared__ __align__(16) float mF[EB * 128];   // 64 KB messages (XOR-swizzled)
    __shared__ int rs[SPANMAX], re[SPANMAX];
    int tid = threadIdx.x, lane = tid & 63, w = tid >> 6;
    int sub = lane >> 4, rA = lane & 15;
    int e0 = blockIdx.x * EB;
    int Fb = w * 16 + sub * 4;                     // feature base 0..124
    int fq = w * 4 + sub;                          // F-group 0..31
    int n0 = dstS[e0];

    // run-boundary tables (gap-fill by run-starter; no init barrier needed)
    if (tid < EB) {
        int d = dstS[e0 + tid];
        int di = min(d - n0, SPANMAX - 1);
        if (tid == 0 || dstS[e0 + tid - 1] != d) {
            rs[di] = tid;
            if (tid > 0) {
                int dp = dstS[e0 + tid - 1];
                for (int g = dp + 1; g < d && (g - n0) < SPANMAX; ++g) {
                    rs[g - n0] = 0; re[g - n0] = 0;
                }
            }
        }
        if (tid == EB - 1 || dstS[e0 + tid + 1] != d) re[di] = tid + 1;
    }

    // folded edge-weight A-frags (registers, L2-resident)
    bf16x8 Ag[3], Ac[3];
    {
        const __bf16* bg_ = WeT + (size_t)(((layer * 2 + 0) * 8 + w) * 3) * 512;
        const __bf16* bc_ = WeT + (size_t)(((layer * 2 + 1) * 8 + w) * 3) * 512;
        #pragma unroll
        for (int ks = 0; ks < 3; ++ks) {
            Ag[ks] = *(const bf16x8*)(bg_ + ks * 512 + lane * 8);
            Ac[ks] = *(const bf16x8*)(bc_ + ks * 512 + lane * 8);
        }
    }

    // hoisted loop-invariant bases
    const char* eb0 = ea2 + ((size_t)(0 + sub) * EP + e0 + rA) * 16;
    const char* eb1 = ea2 + ((size_t)(4 + sub) * EP + e0 + rA) * 16;
    const char* eb2 = ea2 + ((size_t)(8 + sub) * EP + e0 + rA) * 16;
    const int2* sdp = sdS + e0 + rA;
    const float* nbd = NBdF + Fb;
    const __bf16* nbs = NBs2 + fq * 8;
    char* mfp = (char*)mF + rA * 512 + ((w * 64 + sub * 16) ^ ((rA & 7) << 4));

    f32x4 zz = {0.f, 0.f, 0.f, 0.f};
    // depth-2 pipelined register sets (indices fold to constants under unroll)
    bf16x8 bfr[2][3];
    f32x4 dvG[2], dvC[2];
    bf16x8 sv[2];

    // prologue: load nt=0
    {
        int2 sd = sdp[0];
        bfr[0][0] = *(const bf16x8*)(eb0);
        bfr[0][1] = *(const bf16x8*)(eb1);
        bfr[0][2] = *(const bf16x8*)(eb2);
        dvG[0] = *(const f32x4*)(nbd + sd.x);
        dvC[0] = *(const f32x4*)(nbd + sd.x + 128);
        sv[0]  = *(const bf16x8*)(nbs + sd.y);
    }
    #pragma unroll
    for (int nt = 0; nt < EB / 16; ++nt) {
        int cur = nt & 1, nxt = cur ^ 1;
        if (nt + 1 < EB / 16) {   // prefetch next sub-tile
            int2 sd = sdp[(nt + 1) * 16];
            bfr[nxt][0] = *(const bf16x8*)(eb0 + (nt + 1) * 256);
            bfr[nxt][1] = *(const bf16x8*)(eb1 + (nt + 1) * 256);
            bfr[nxt][2] = *(const bf16x8*)(eb2 + (nt + 1) * 256);
            dvG[nxt] = *(const f32x4*)(nbd + sd.x);
            dvC[nxt] = *(const f32x4*)(nbd + sd.x + 128);
            sv[nxt]  = *(const bf16x8*)(nbs + sd.y);
        }
        // dst-side node term enters as the MFMA C-init (free)
        f32x4 aG = dvG[cur], aC = dvC[cur];
        #pragma unroll
        for (int ks = 0; ks < 3; ++ks) {
            aG = __builtin_amdgcn_mfma_f32_16x16x32_bf16(Ag[ks], bfr[cur][ks], aG, 0, 0, 0);
            aC = __builtin_amdgcn_mfma_f32_16x16x32_bf16(Ac[ks], bfr[cur][ks], aC, 0, 0, 0);
        }
        f32x4 mv;
        #pragma unroll
        for (int r = 0; r < 4; ++r) {
            float gi = aG[r] + (float)sv[cur][r];
            float ci = aC[r] + (float)sv[cur][4 + r];
            mv[r] = sigmoidf_(gi) * softplusf_(ci);
        }
        *(f32x4*)(mfp + nt * 8192) = mv;
    }
    __syncthreads();
    // segment-sum over runs -> h (16B feature granularity)
    int span = min(dstS[e0 + EB - 1] - n0 + 1, SPANMAX);
    int items = span * 32;
    for (int it = tid; it < items; it += 512) {
        int ln = it >> 5, fqq = it & 31;
        int rs_ = rs[ln], re_ = re[ln];
        f32x4 s = zz;
        for (int e = rs_; e < re_; ++e) {
            f32x4 v = *(const f32x4*)((char*)mF + e * 512 + ((fqq * 16) ^ ((e & 7) << 4)));
            s[0] += v[0]; s[1] += v[1]; s[2] += v[2]; s[3] += v[3];
        }
        int node = n0 + ln;
        float* dp = h + (size_t)node * 128 + fqq * 4;
        if (ln == 0 || ln == span - 1) {
            atomicAdd(dp + 0, s[0]); atomicAdd(dp + 1, s[1]);
            atomicAdd(dp + 2, s[2]); atomicAdd(dp + 3, s[3]);
        } else {
            dp[0] += s[0]; dp[1] += s[1]; dp[2] += s[2]; dp[3] += s[3];
        }
    }
}

// ---------------------------------------------------------------------------
// Readout
// ---------------------------------------------------------------------------
__global__ void __launch_bounds__(128) k_readout(const float* __restrict__ h,
    const int* __restrict__ batch, const float* __restrict__ W1,
    const float* __restrict__ b1, const float* __restrict__ W2,
    const float* __restrict__ b2, float* __restrict__ out) {
    int g = blockIdx.x, tid = threadIdx.x;
    __shared__ int se[2];
    __shared__ float pl[NF];
    __shared__ float red[2];
    if (tid < 2) {
        int target = g + tid;
        int lo = 0, hi = N_NODES;
        while (lo < hi) { int mid = (lo + hi) >> 1; if (batch[mid] < target) lo = mid + 1; else hi = mid; }
        se[tid] = lo;
    }
    __syncthreads();
    int s = se[0], e = se[1];
    float sum = 0.0f;
    for (int n = s; n < e; ++n) sum += h[(size_t)n * NF + tid];
    float cnt = (float)max(e - s, 1);
    pl[tid] = sum / cnt;
    __syncthreads();
    float acc = b1[tid];
    for (int c = 0; c < NF; ++c) acc += pl[c] * W1[c * NF + tid];
    float hid = siluf_(acc);
    float v = hid * W2[tid];
    #pragma unroll
    for (int off = 32; off > 0; off >>= 1) v += __shfl_down(v, off);
    if ((tid & 63) == 0) red[tid >> 6] = v;
    __syncthreads();
    if (tid == 0) out[g] = red[0] + red[1] + b2[0];
}

// ---------------------------------------------------------------------------
extern "C" void kernel_launch(void* const* d_in, const int* in_sizes, int n_in,
                              void* d_out, int out_size, void* d_ws, size_t ws_size,
                              hipStream_t stream) {
    const float* x     = (const float*)d_in[0];
    const int*   eidx  = (const int*)d_in[1];
    const float* sh    = (const float*)d_in[2];
    const float* edist = (const float*)d_in[3];
    const int*   batch = (const int*)d_in[4];
    const float* W_emb = (const float*)d_in[5];
    const float* b_emb = (const float*)d_in[6];
    const float* shW1  = (const float*)d_in[7];
    const float* shB1  = (const float*)d_in[8];
    const float* shW2  = (const float*)d_in[9];
    const float* shB2  = (const float*)d_in[10];
    const float* rbW1  = (const float*)d_in[11];
    const float* rbB1  = (const float*)d_in[12];
    const float* rbW2  = (const float*)d_in[13];
    const float* rbB2  = (const float*)d_in[14];
    const float* Wg    = (const float*)d_in[15];
    const float* bg    = (const float*)d_in[16];
    const float* Wc    = (const float*)d_in[17];
    const float* bc    = (const float*)d_in[18];
    const float* fcW1  = (const float*)d_in[19];
    const float* fcb1  = (const float*)d_in[20];
    const float* fcW2  = (const float*)d_in[21];
    const float* fcb2  = (const float*)d_in[22];
    const int* srcI = eidx;
    const int* dstI = eidx + N_EDGES;

    char* ws = (char*)d_ws;
    // Total footprint 226.2 MB (ws_size >= 231.8 MB proven by R16's pass).
    float*  h     = (float*)(ws + 0);              // 25,600,512 (50001 rows; last = dummy)
    char*   ea2   = (char*)(ws + 25600512);        // 96,018,432 (12 planes x EP x 16B)
    int*    dstS  = (int*)(ws + 121618944);        //  2,000,384
    int2*   sdS   = (int2*)(ws + 123619328);       //  4,000,768 (row offsets x256)
    int*    deg   = (int*)(ws + 127620096);        //    200,000
    int*    curs  = (int*)(ws + 127820096);        //    200,000
    float*  distS = (float*)(ws + 128020096);      //  2,000,384
    float*  shS   = (float*)(ws + 130020480);      // 18,003,456
    __bf16* WeT   = (__bf16*)(ws + 148023936);     //    245,760
    __bf16* WnT   = (__bf16*)(ws + 148269696);     //    655,360
    float*  Wfold = (float*)(ws + 148925056);      //    491,520
    float*  bF    = (float*)(ws + 149416576);      //      5,120
    float*  NBdF  = (float*)(ws + 149421696);      // 51,200,000 (f32 dst side)
    __bf16* NBs2  = (__bf16*)(ws + 200621696);     // 25,600,000 -> ends 226,221,696

    hipMemsetAsync(deg, 0, (size_t)N_NODES * sizeof(int), stream);
    k_fold<<<480, 256, 0, stream>>>(Wg, Wc, rbW2, rbB2, shW2, shB2, bg, bc, Wfold, bF);
    k_prep_w<<<220, 256, 0, stream>>>(Wg, Wc, Wfold, WeT, WnT);
    k_embed<<<N_NODES / 8, 256, 0, stream>>>(x, W_emb, b_emb, h);
    k_deg<<<(N_EDGES + 255) / 256, 256, 0, stream>>>(dstI, deg);
    k_scan<<<1, 1024, 0, stream>>>(deg, curs);
    k_scatter<<<(N_EDGES + 255) / 256, 256, 0, stream>>>(srcI, dstI, edist, sh, curs,
                                                         dstS, sdS, distS, shS);
    k_edge<<<(N_EDGES + 255) / 256, 256, 0, stream>>>(distS, shS, shW1, shB1,
                                                      rbW1, rbB1, ea2);
    k_pad<<<1, 128, 0, stream>>>(dstS, sdS, ea2);
    for (int l = 0; l < N_LAYERS; ++l) {
        const float* bgF = bF + (l * 2 + 0) * 128;
        const float* bcF = bF + (l * 2 + 1) * 128;
        k_node<<<(N_NODES + 31) / 32, 256, 0, stream>>>(h, WnT, bgF, bcF, NBdF, NBs2, l);
        k_msg<<<EP / EB, 512, 0, stream>>>(ea2, dstS, sdS, WeT, NBdF, NBs2, h, l);
    }
    k_readout<<<N_GRAPHS, 128, 0, stream>>>(h, batch, fcW1, fcb1, fcW2, fcb2, (float*)d_out);
}

// Round 18
// 1071.669 us; speedup vs baseline: 1.1419x; 1.0319x over previous
//
#include <hip/hip_runtime.h>

typedef __bf16 bf16x8 __attribute__((ext_vector_type(8)));
typedef __bf16 bf16x4 __attribute__((ext_vector_type(4)));
typedef float  f32x4  __attribute__((ext_vector_type(4)));

#define N_NODES  50000
#define N_EDGES  500000
#define EB       128         // edges per k_msg block
#define EP       500096      // padded edge count (multiple of EB)
#define NCH      12          // 16B chunks per edge row (96 bf16)
#define N_GRAPHS 1024
#define NF       128
#define IN_DIM   92
#define N_LAYERS 5
#define SPANMAX  256

__device__ __forceinline__ float sigmoidf_(float x) { return 1.0f / (1.0f + __expf(-x)); }
__device__ __forceinline__ float softplusf_(float x) {
    return fmaxf(x, 0.0f) + __logf(1.0f + __expf(-fabsf(x)));
}
__device__ __forceinline__ float siluf_(float x) { return x * sigmoidf_(x); }

// ---------------------------------------------------------------------------
// Fold the edge-MLP second stage into layer weights (parallel).
// ---------------------------------------------------------------------------
__global__ void __launch_bounds__(256) k_fold(const float* __restrict__ Wg,
    const float* __restrict__ Wc, const float* __restrict__ rbW2,
    const float* __restrict__ rbB2, const float* __restrict__ shW2,
    const float* __restrict__ shB2, const float* __restrict__ bg,
    const float* __restrict__ bc, float* __restrict__ Wfold,
    float* __restrict__ bF) {
    int lg = blockIdx.x / 48, chunk = blockIdx.x % 48;
    int l = lg >> 1, g = lg & 1;
    const float* W = (g ? Wc : Wg) + (size_t)l * 384 * 128;
    int idx = chunk * 256 + threadIdx.x;
    int r = idx >> 7, n = idx & 127;
    float s = 0.f;
    if (r < 64) {
        for (int o = 0; o < 64; ++o) s += rbW2[r * 64 + o] * W[(256 + o) * 128 + n];
    } else {
        int j = r - 64;
        for (int o = 0; o < 64; ++o) s += shW2[j * 64 + o] * W[(320 + o) * 128 + n];
    }
    Wfold[(size_t)lg * 12288 + idx] = s;
    if (chunk == 0 && threadIdx.x < 128) {
        const float* bsrc = (g ? bc : bg) + l * 128;
        float b = bsrc[threadIdx.x];
        for (int o = 0; o < 64; ++o) b += rbB2[o] * W[(256 + o) * 128 + threadIdx.x];
        for (int o = 0; o < 64; ++o) b += shB2[o] * W[(320 + o) * 128 + threadIdx.x];
        bF[lg * 128 + threadIdx.x] = b;
    }
}

// ---------------------------------------------------------------------------
// Weight prep: WeT = A-frags of Wfold^T; WnT = A-frags of node weights.
// ---------------------------------------------------------------------------
__global__ void __launch_bounds__(256) k_prep_w(const float* __restrict__ Wg,
                                                const float* __restrict__ Wc,
                                                const float* __restrict__ Wfold,
                                                __bf16* __restrict__ WeT,
                                                __bf16* __restrict__ WnT) {
    int t = blockIdx.x * 256 + threadIdx.x;
    if (t >= (240 + 640) * 64) return;
    int frag = t >> 6, lane = t & 63;
    int sub = lane >> 4, mm = lane & 15;
    bf16x8 v;
    if (frag < 240) {
        int lg = frag / 24; int r = frag % 24;
        int m = r / 3; int ks = r % 3;
        #pragma unroll
        for (int j = 0; j < 8; ++j) {
            int k = ks * 32 + sub * 8 + j;
            v[j] = (__bf16)Wfold[(size_t)lg * 12288 + (size_t)k * 128 + m * 16 + mm];
        }
        *(bf16x8*)(WeT + (size_t)frag * 512 + lane * 8) = v;
    } else {
        int f2 = frag - 240;
        int l = f2 / 128; int r = f2 % 128;
        int m = r >> 2; int ks = r & 3;
        int F = m * 16 + mm;
        #pragma unroll
        for (int j = 0; j < 8; ++j) {
            int k = ks * 32 + sub * 8 + j;
            float val;
            if      (F < 128) val = Wg[(size_t)l*384*128 + (size_t)k*128 + F];
            else if (F < 256) val = Wc[(size_t)l*384*128 + (size_t)k*128 + (F-128)];
            else if (F < 384) val = Wg[(size_t)l*384*128 + (size_t)(128+k)*128 + (F-256)];
            else              val = Wc[(size_t)l*384*128 + (size_t)(128+k)*128 + (F-384)];
            v[j] = (__bf16)val;
        }
        *(bf16x8*)(WnT + (size_t)f2 * 512 + lane * 8) = v;
    }
}

// ---------------------------------------------------------------------------
// CSR build
// ---------------------------------------------------------------------------
__global__ void __launch_bounds__(256) k_deg(const int* __restrict__ dstI,
                                             int* __restrict__ deg) {
    int e = blockIdx.x * 256 + threadIdx.x;
    if (e < N_EDGES) atomicAdd(&deg[dstI[e]], 1);
}

__global__ void __launch_bounds__(1024) k_scan(const int* __restrict__ deg,
                                               int* __restrict__ cursor) {
    __shared__ int ps[1024];
    int t = threadIdx.x;
    const int C = (N_NODES + 1023) / 1024;
    int base = t * C;
    int s = 0;
    for (int i = 0; i < C; ++i) { int idx = base + i; if (idx < N_NODES) s += deg[idx]; }
    ps[t] = s;
    __syncthreads();
    for (int off = 1; off < 1024; off <<= 1) {
        int v = 0;
        if (t >= off) v = ps[t - off];
        __syncthreads();
        if (t >= off) ps[t] += v;
        __syncthreads();
    }
    int run = (t > 0) ? ps[t - 1] : 0;
    for (int i = 0; i < C; ++i) {
        int idx = base + i;
        if (idx < N_NODES) { cursor[idx] = run; run += deg[idx]; }
    }
}

// ---------------------------------------------------------------------------
// Scatter: sorted dst, pre-scaled (dst,src) row offsets (256 elems/node),
// and gathered per-edge raw features in sorted order.
// ---------------------------------------------------------------------------
__global__ void __launch_bounds__(256) k_scatter(const int* __restrict__ srcI,
                                                 const int* __restrict__ dstI,
                                                 const float* __restrict__ edist,
                                                 const float* __restrict__ sh,
                                                 int* __restrict__ cursor,
                                                 int* __restrict__ dstS,
                                                 int2* __restrict__ sdS,
                                                 float* __restrict__ distS,
                                                 float* __restrict__ shS) {
    int e = blockIdx.x * 256 + threadIdx.x;
    if (e >= N_EDGES) return;
    int d = dstI[e];
    int p = atomicAdd(&cursor[d], 1);
    dstS[p] = d;
    sdS[p] = make_int2(d * 256, srcI[e] * 256);
    distS[p] = edist[e];
    #pragma unroll
    for (int i = 0; i < 9; ++i) shS[(size_t)p * 9 + i] = sh[(size_t)e * 9 + i];
}

// ---------------------------------------------------------------------------
// Pad entries [N_EDGES, EP).
// ---------------------------------------------------------------------------
__global__ void __launch_bounds__(128) k_pad(int* __restrict__ dstS,
                                             int2* __restrict__ sdS,
                                             char* __restrict__ ea2) {
    int i = threadIdx.x;
    if (i < EP - N_EDGES) {
        dstS[N_EDGES + i] = N_NODES;
        sdS[N_EDGES + i] = make_int2((N_NODES - 1) * 256, 0);
        uint4 z = {0, 0, 0, 0};
        for (int p = 0; p < NCH; ++p)
            *(uint4*)(ea2 + ((size_t)p * EP + N_EDGES + i) * 16) = z;
    }
}

// ---------------------------------------------------------------------------
// Atom embedding: h = x @ W_emb + b_emb (f32)
// ---------------------------------------------------------------------------
__global__ void __launch_bounds__(256) k_embed(const float* __restrict__ x,
                                               const float* __restrict__ W,
                                               const float* __restrict__ b,
                                               float* __restrict__ h) {
    int tid = threadIdx.x;
    int f = tid & 127;
    int nb = blockIdx.x * 8 + (tid >> 7) * 4;
    const float* x0 = x + (size_t)nb * IN_DIM;
    float a0 = b[f], a1 = a0, a2 = a0, a3 = a0;
    #pragma unroll 4
    for (int k = 0; k < IN_DIM; ++k) {
        float wv = W[k * NF + f];
        a0 = fmaf(x0[k], wv, a0);
        a1 = fmaf(x0[IN_DIM + k], wv, a1);
        a2 = fmaf(x0[2 * IN_DIM + k], wv, a2);
        a3 = fmaf(x0[3 * IN_DIM + k], wv, a3);
    }
    float accs[4] = {a0, a1, a2, a3};
    #pragma unroll
    for (int r = 0; r < 4; ++r)
        h[(size_t)(nb + r) * NF + f] = accs[r];
}

// ---------------------------------------------------------------------------
// Edge hidden features eh[e][96] — streaming, chunk-plane output.
// ---------------------------------------------------------------------------
__global__ void __launch_bounds__(256) k_edge(const float* __restrict__ distS,
    const float* __restrict__ shS,
    const float* __restrict__ shW1, const float* __restrict__ shB1,
    const float* __restrict__ rbW1, const float* __restrict__ rbB1,
    char* __restrict__ ea2) {
    __shared__ float wf[4480];
    int tid = threadIdx.x;
    int p = blockIdx.x * 256 + tid;
    bool pv = p < N_EDGES;
    int pc = pv ? p : 0;
    float dv = distS[pc];
    float shv[9];
    #pragma unroll
    for (int i = 0; i < 9; ++i) shv[i] = shS[(size_t)pc * 9 + i];
    for (int i = tid; i < 288;  i += 256) wf[i]        = shW1[i];
    for (int i = tid; i < 32;   i += 256) wf[288 + i]  = shB1[i];
    for (int i = tid; i < 4096; i += 256) wf[320 + i]  = rbW1[i];
    for (int i = tid; i < 64;   i += 256) wf[4416 + i] = rbB1[i];
    __syncthreads();
    if (!pv) return;

    const float* W1 = wf + 320; const float* B1 = wf + 4416;
    float invd = 1.0f / dv;
    const float step = (1.4f - 0.125f) / 63.0f;
    const float gam = 1.0f / (step * step);
    float hid[64];
    #pragma unroll
    for (int j = 0; j < 64; ++j) hid[j] = B1[j];
    for (int i = 0; i < 64; ++i) {
        float c = 0.125f + i * step;
        float d = invd - c;
        float r = __expf(-gam * d * d);
        #pragma unroll
        for (int j = 0; j < 64; ++j) hid[j] += r * W1[i * 64 + j];
    }
    #pragma unroll
    for (int o8 = 0; o8 < 8; ++o8) {
        bf16x8 v;
        #pragma unroll
        for (int j = 0; j < 8; ++j) v[j] = (__bf16)siluf_(hid[o8 * 8 + j]);
        *(bf16x8*)(ea2 + ((size_t)o8 * EP + p) * 16) = v;
    }
    const float* sW1 = wf; const float* sB1 = wf + 288;
    float h2[32];
    #pragma unroll
    for (int j = 0; j < 32; ++j) h2[j] = sB1[j];
    #pragma unroll
    for (int i = 0; i < 9; ++i) {
        float si = shv[i];
        #pragma unroll
        for (int j = 0; j < 32; ++j) h2[j] += si * sW1[i * 32 + j];
    }
    #pragma unroll
    for (int o8 = 0; o8 < 4; ++o8) {
        bf16x8 v;
        #pragma unroll
        for (int j = 0; j < 8; ++j) v[j] = (__bf16)siluf_(h2[o8 * 8 + j]);
        *(bf16x8*)(ea2 + ((size_t)(8 + o8) * EP + p) * 16) = v;
    }
}

// ---------------------------------------------------------------------------
// Per-node GEMM -> SPLIT packed bf16 buffers (full line utilization per side):
// NBd2[node][fq][8] = [gd(4) | cd(4)]   (dst side)
// NBs2[node][fq][8] = [gs(4) | cs(4)]   (src side)
// ---------------------------------------------------------------------------
__global__ void __launch_bounds__(256) k_node(const float* __restrict__ h,
                                              const __bf16* __restrict__ WnT,
                                              const float* __restrict__ bgl,
                                              const float* __restrict__ bcl,
                                              __bf16* __restrict__ NBd2,
                                              __bf16* __restrict__ NBs2, int layer) {
    int tid = threadIdx.x, lane = tid & 63, w = tid >> 6;
    int sub = lane >> 4, rA = lane & 15;
    int node0 = blockIdx.x * 32;
    bf16x8 Bf[2][4];
    #pragma unroll
    for (int nt = 0; nt < 2; ++nt)
        #pragma unroll
        for (int ks = 0; ks < 4; ++ks) {
            int node = min(node0 + nt * 16 + rA, N_NODES - 1);
            const float* hr = h + (size_t)node * 128 + ks * 32 + sub * 8;
            f32x4 u0 = *(const f32x4*)hr;
            f32x4 u1 = *(const f32x4*)(hr + 4);
            bf16x8 bv;
            bv[0] = (__bf16)u0[0]; bv[1] = (__bf16)u0[1];
            bv[2] = (__bf16)u0[2]; bv[3] = (__bf16)u0[3];
            bv[4] = (__bf16)u1[0]; bv[5] = (__bf16)u1[1];
            bv[6] = (__bf16)u1[2]; bv[7] = (__bf16)u1[3];
            Bf[nt][ks] = bv;
        }
    const __bf16* Wbase = WnT + (size_t)layer * 128 * 512;
    f32x4 acc[8][2];
    f32x4 zz = {0.f, 0.f, 0.f, 0.f};
    #pragma unroll
    for (int mt = 0; mt < 8; ++mt) { acc[mt][0] = zz; acc[mt][1] = zz; }
    for (int mt = 0; mt < 8; ++mt) {
        int gm = w * 8 + mt;
        bf16x8 Af[4];
        #pragma unroll
        for (int ks = 0; ks < 4; ++ks)
            Af[ks] = *(const bf16x8*)(Wbase + (size_t)(gm * 4 + ks) * 512 + lane * 8);
        #pragma unroll
        for (int nt = 0; nt < 2; ++nt) {
            f32x4 a = acc[mt][nt];
            #pragma unroll
            for (int ks = 0; ks < 4; ++ks)
                a = __builtin_amdgcn_mfma_f32_16x16x32_bf16(Af[ks], Bf[nt][ks], a, 0, 0, 0);
            acc[mt][nt] = a;
        }
    }
    #pragma unroll
    for (int mt = 0; mt < 8; ++mt) {
        int F = (w * 8 + mt) * 16 + sub * 4;     // global feature 0..511
        int part = F >> 7;                       // 0=gd 1=cd 2=gs 3=cs
        int fq = (F & 127) >> 2;                 // F-group 0..31
        f32x4 bias = zz;
        if (part == 0)      bias = *(const f32x4*)(bgl + (F & 127));
        else if (part == 1) bias = *(const f32x4*)(bcl + (F & 127));
        __bf16* buf = (part < 2) ? NBd2 : NBs2;
        int off = fq * 8 + (part & 1) * 4;
        #pragma unroll
        for (int nt = 0; nt < 2; ++nt) {
            int node = node0 + nt * 16 + rA;
            if (node >= N_NODES) continue;
            f32x4 vv = acc[mt][nt];
            vv[0] += bias[0]; vv[1] += bias[1]; vv[2] += bias[2]; vv[3] += bias[3];
            bf16x4 bv;
            bv[0] = (__bf16)vv[0]; bv[1] = (__bf16)vv[1];
            bv[2] = (__bf16)vv[2]; bv[3] = (__bf16)vv[3];
            *(bf16x4*)(buf + (size_t)node * 256 + off) = bv;
        }
    }
}

// ---------------------------------------------------------------------------
// Message layer, dst-sorted, all blocks full (padded edges -> dummy node).
// Per nt per thread: 3 bfr + 1 dst-NB (16B) + 1 src-NB (16B) + 1 int2 idx.
// ---------------------------------------------------------------------------
__global__ void __launch_bounds__(512) k_msg(
    const char* __restrict__ ea2, const int* __restrict__ dstS,
    const int2* __restrict__ sdS, const __bf16* __restrict__ WeT,
    const __bf16* __restrict__ NBd2, const __bf16* __restrict__ NBs2,
    float* __restrict__ h, int layer)
{
    __shared__ __align__(16) float mF[EB * 128];   // 64 KB messages (XOR-swizzled)
    __shared__ int rs[SPANMAX], re[SPANMAX];
    int tid = threadIdx.x, lane = tid & 63, w = tid >> 6;
    int sub = lane >> 4, rA = lane & 15;
    int e0 = blockIdx.x * EB;
    int fq = w * 4 + sub;                          // F-group 0..31
    int n0 = dstS[e0];

    // run-boundary tables (gap-fill by run-starter; no init barrier needed)
    if (tid < EB) {
        int d = dstS[e0 + tid];
        int di = min(d - n0, SPANMAX - 1);
        if (tid == 0 || dstS[e0 + tid - 1] != d) {
            rs[di] = tid;
            if (tid > 0) {
                int dp = dstS[e0 + tid - 1];
                for (int g = dp + 1; g < d && (g - n0) < SPANMAX; ++g) {
                    rs[g - n0] = 0; re[g - n0] = 0;
                }
            }
        }
        if (tid == EB - 1 || dstS[e0 + tid + 1] != d) re[di] = tid + 1;
    }

    // folded edge-weight A-frags (registers, L2-resident)
    bf16x8 Ag[3], Ac[3];
    {
        const __bf16* bg_ = WeT + (size_t)(((layer * 2 + 0) * 8 + w) * 3) * 512;
        const __bf16* bc_ = WeT + (size_t)(((layer * 2 + 1) * 8 + w) * 3) * 512;
        #pragma unroll
        for (int ks = 0; ks < 3; ++ks) {
            Ag[ks] = *(const bf16x8*)(bg_ + ks * 512 + lane * 8);
            Ac[ks] = *(const bf16x8*)(bc_ + ks * 512 + lane * 8);
        }
    }

    // hoisted loop-invariant bases
    const char* eb0 = ea2 + ((size_t)(0 + sub) * EP + e0 + rA) * 16;
    const char* eb1 = ea2 + ((size_t)(4 + sub) * EP + e0 + rA) * 16;
    const char* eb2 = ea2 + ((size_t)(8 + sub) * EP + e0 + rA) * 16;
    const int2* sdp = sdS + e0 + rA;
    const __bf16* nbd = NBd2 + fq * 8;
    const __bf16* nbs = NBs2 + fq * 8;
    char* mfp = (char*)mF + rA * 512 + ((w * 64 + sub * 16) ^ ((rA & 7) << 4));

    f32x4 zz = {0.f, 0.f, 0.f, 0.f};
    // depth-2 pipelined register sets (indices fold to constants under unroll)
    bf16x8 bfr[2][3];
    bf16x8 dv[2], sv[2];

    // prologue: load nt=0
    {
        int2 sd = sdp[0];
        bfr[0][0] = *(const bf16x8*)(eb0);
        bfr[0][1] = *(const bf16x8*)(eb1);
        bfr[0][2] = *(const bf16x8*)(eb2);
        dv[0] = *(const bf16x8*)(nbd + sd.x);
        sv[0] = *(const bf16x8*)(nbs + sd.y);
    }
    #pragma unroll
    for (int nt = 0; nt < EB / 16; ++nt) {
        int cur = nt & 1, nxt = cur ^ 1;
        if (nt + 1 < EB / 16) {   // prefetch next sub-tile
            int2 sd = sdp[(nt + 1) * 16];
            bfr[nxt][0] = *(const bf16x8*)(eb0 + (nt + 1) * 256);
            bfr[nxt][1] = *(const bf16x8*)(eb1 + (nt + 1) * 256);
            bfr[nxt][2] = *(const bf16x8*)(eb2 + (nt + 1) * 256);
            dv[nxt] = *(const bf16x8*)(nbd + sd.x);
            sv[nxt] = *(const bf16x8*)(nbs + sd.y);
        }
        f32x4 aG = zz, aC = zz;
        #pragma unroll
        for (int ks = 0; ks < 3; ++ks) {
            aG = __builtin_amdgcn_mfma_f32_16x16x32_bf16(Ag[ks], bfr[cur][ks], aG, 0, 0, 0);
            aC = __builtin_amdgcn_mfma_f32_16x16x32_bf16(Ac[ks], bfr[cur][ks], aC, 0, 0, 0);
        }
        f32x4 mv;
        #pragma unroll
        for (int r = 0; r < 4; ++r) {
            float gi = aG[r] + (float)dv[cur][r] + (float)sv[cur][r];
            float ci = aC[r] + (float)dv[cur][4 + r] + (float)sv[cur][4 + r];
            mv[r] = sigmoidf_(gi) * softplusf_(ci);
        }
        *(f32x4*)(mfp + nt * 8192) = mv;
    }
    __syncthreads();
    // segment-sum over runs -> h (16B feature granularity)
    int span = min(dstS[e0 + EB - 1] - n0 + 1, SPANMAX);
    int items = span * 32;
    for (int it = tid; it < items; it += 512) {
        int ln = it >> 5, fqq = it & 31;
        int rs_ = rs[ln], re_ = re[ln];
        f32x4 s = zz;
        for (int e = rs_; e < re_; ++e) {
            f32x4 v = *(const f32x4*)((char*)mF + e * 512 + ((fqq * 16) ^ ((e & 7) << 4)));
            s[0] += v[0]; s[1] += v[1]; s[2] += v[2]; s[3] += v[3];
        }
        int node = n0 + ln;
        float* dp = h + (size_t)node * 128 + fqq * 4;
        if (ln == 0 || ln == span - 1) {
            atomicAdd(dp + 0, s[0]); atomicAdd(dp + 1, s[1]);
            atomicAdd(dp + 2, s[2]); atomicAdd(dp + 3, s[3]);
        } else {
            dp[0] += s[0]; dp[1] += s[1]; dp[2] += s[2]; dp[3] += s[3];
        }
    }
}

// ---------------------------------------------------------------------------
// Readout
// ---------------------------------------------------------------------------
__global__ void __launch_bounds__(128) k_readout(const float* __restrict__ h,
    const int* __restrict__ batch, const float* __restrict__ W1,
    const float* __restrict__ b1, const float* __restrict__ W2,
    const float* __restrict__ b2, float* __restrict__ out) {
    int g = blockIdx.x, tid = threadIdx.x;
    __shared__ int se[2];
    __shared__ float pl[NF];
    __shared__ float red[2];
    if (tid < 2) {
        int target = g + tid;
        int lo = 0, hi = N_NODES;
        while (lo < hi) { int mid = (lo + hi) >> 1; if (batch[mid] < target) lo = mid + 1; else hi = mid; }
        se[tid] = lo;
    }
    __syncthreads();
    int s = se[0], e = se[1];
    float sum = 0.0f;
    for (int n = s; n < e; ++n) sum += h[(size_t)n * NF + tid];
    float cnt = (float)max(e - s, 1);
    pl[tid] = sum / cnt;
    __syncthreads();
    float acc = b1[tid];
    for (int c = 0; c < NF; ++c) acc += pl[c] * W1[c * NF + tid];
    float hid = siluf_(acc);
    float v = hid * W2[tid];
    #pragma unroll
    for (int off = 32; off > 0; off >>= 1) v += __shfl_down(v, off);
    if ((tid & 63) == 0) red[tid >> 6] = v;
    __syncthreads();
    if (tid == 0) out[g] = red[0] + red[1] + b2[0];
}

// ---------------------------------------------------------------------------
extern "C" void kernel_launch(void* const* d_in, const int* in_sizes, int n_in,
                              void* d_out, int out_size, void* d_ws, size_t ws_size,
                              hipStream_t stream) {
    const float* x     = (const float*)d_in[0];
    const int*   eidx  = (const int*)d_in[1];
    const float* sh    = (const float*)d_in[2];
    const float* edist = (const float*)d_in[3];
    const int*   batch = (const int*)d_in[4];
    const float* W_emb = (const float*)d_in[5];
    const float* b_emb = (const float*)d_in[6];
    const float* shW1  = (const float*)d_in[7];
    const float* shB1  = (const float*)d_in[8];
    const float* shW2  = (const float*)d_in[9];
    const float* shB2  = (const float*)d_in[10];
    const float* rbW1  = (const float*)d_in[11];
    const float* rbB1  = (const float*)d_in[12];
    const float* rbW2  = (const float*)d_in[13];
    const float* rbB2  = (const float*)d_in[14];
    const float* Wg    = (const float*)d_in[15];
    const float* bg    = (const float*)d_in[16];
    const float* Wc    = (const float*)d_in[17];
    const float* bc    = (const float*)d_in[18];
    const float* fcW1  = (const float*)d_in[19];
    const float* fcb1  = (const float*)d_in[20];
    const float* fcW2  = (const float*)d_in[21];
    const float* fcb2  = (const float*)d_in[22];
    const int* srcI = eidx;
    const int* dstI = eidx + N_EDGES;

    char* ws = (char*)d_ws;
    float*  h     = (float*)(ws + 0);              // 25,600,512 (50001 rows; last = dummy)
    char*   ea2   = (char*)(ws + 25600512);        // 96,018,432 (12 planes x EP x 16B)
    int*    dstS  = (int*)(ws + 121618944);        //  2,000,384 (EP entries)
    int2*   sdS   = (int2*)(ws + 123619328);       //  4,000,768 (EP entries, elem offsets)
    int*    deg   = (int*)(ws + 127620096);        //    200,000
    int*    curs  = (int*)(ws + 127820096);        //    200,000
    float*  distS = (float*)(ws + 128020096);      //  2,000,384
    float*  shS   = (float*)(ws + 130020480);      // 18,003,456
    __bf16* WeT   = (__bf16*)(ws + 148023936);     //    245,760
    __bf16* WnT   = (__bf16*)(ws + 148269696);     //    655,360
    float*  Wfold = (float*)(ws + 148925056);      //    491,520
    float*  bF    = (float*)(ws + 149416576);      //      5,120
    __bf16* NBd2  = (__bf16*)(ws + 149421696);     // 25,600,000
    __bf16* NBs2  = (__bf16*)(ws + 175021696);     // 25,600,000  -> ends 200.6 MB

    hipMemsetAsync(deg, 0, (size_t)N_NODES * sizeof(int), stream);
    k_fold<<<480, 256, 0, stream>>>(Wg, Wc, rbW2, rbB2, shW2, shB2, bg, bc, Wfold, bF);
    k_prep_w<<<220, 256, 0, stream>>>(Wg, Wc, Wfold, WeT, WnT);
    k_embed<<<N_NODES / 8, 256, 0, stream>>>(x, W_emb, b_emb, h);
    k_deg<<<(N_EDGES + 255) / 256, 256, 0, stream>>>(dstI, deg);
    k_scan<<<1, 1024, 0, stream>>>(deg, curs);
    k_scatter<<<(N_EDGES + 255) / 256, 256, 0, stream>>>(srcI, dstI, edist, sh, curs,
                                                         dstS, sdS, distS, shS);
    k_edge<<<(N_EDGES + 255) / 256, 256, 0, stream>>>(distS, shS, shW1, shB1,
                                                      rbW1, rbB1, ea2);
    k_pad<<<1, 128, 0, stream>>>(dstS, sdS, ea2);
    for (int l = 0; l < N_LAYERS; ++l) {
        const float* bgF = bF + (l * 2 + 0) * 128;
        const float* bcF = bF + (l * 2 + 1) * 128;
        k_node<<<(N_NODES + 31) / 32, 256, 0, stream>>>(h, WnT, bgF, bcF, NBd2, NBs2, l);
        k_msg<<<EP / EB, 512, 0, stream>>>(ea2, dstS, sdS, WeT, NBd2, NBs2, h, l);
    }
    k_readout<<<N_GRAPHS, 128, 0, stream>>>(h, batch, fcW1, fcb1, fcW2, fcb2, (float*)d_out);
}